// Round 2
// baseline (290.043 us; speedup 1.0000x reference)
//
#include <hip/hip_runtime.h>

// L2O optimizer fused kernel — bf16-MFMA, VALU-lean activations (v_exp + v_rcp),
// native bf16 converts, per-wave LDS staging with wave-local fences.
// Layouts:
//  * B-frag LDS [k/8][n][k%8] (bf16): lane l reads 16B at [l>>4][nt*16+(l&15)].
//  * A and B frags use the SAME k-slot mapping -> correctness independent of HW k-order.
//  * C/D layout (HW-verified): col = lane&15, row = (lane>>4)*4 + reg.

typedef __attribute__((ext_vector_type(8))) short bf16x8;
typedef __attribute__((ext_vector_type(4))) float f32x4;

#define HH 32
#define LL 10
#define NG 128

__device__ __forceinline__ short f2bf(float x) {
  __bf16 b = (__bf16)x;                 // HW v_cvt (pairs fuse to v_cvt_pk_bf16_f32)
  return __builtin_bit_cast(short, b);
}
// sigmoid/tanh via v_exp_f32 + raw v_rcp_f32 (~1 ulp; bf16-scale tolerance)
__device__ __forceinline__ float fsig(float x) {
  return __builtin_amdgcn_rcpf(1.0f + __expf(-x));
}
__device__ __forceinline__ float ftanh(float x) {
  return fmaf(2.0f, __builtin_amdgcn_rcpf(1.0f + __expf(-2.0f * x)), -1.0f);
}

__global__ __launch_bounds__(256, 4) void l2o_fused(
    const float* __restrict__ x, const float* __restrict__ grad,
    const float* __restrict__ h0, const float* __restrict__ c0,
    const float* __restrict__ h1, const float* __restrict__ c1,
    const float* __restrict__ W1, const float* __restrict__ b1,
    const float* __restrict__ W2, const float* __restrict__ b2,
    const float* __restrict__ Wih0, const float* __restrict__ Whh0,
    const float* __restrict__ bih0, const float* __restrict__ bhh0,
    const float* __restrict__ Wih1, const float* __restrict__ Whh1,
    const float* __restrict__ bih1, const float* __restrict__ bhh1,
    const float* __restrict__ Wfc, const float* __restrict__ bfc,
    float* __restrict__ out, int BNi)
{
  const size_t BN = (size_t)BNi;
  float* __restrict__ xout  = out;
  float* __restrict__ h0out = out + BN;
  float* __restrict__ c0out = out + BN + BN * HH;
  float* __restrict__ h1out = out + BN + 2 * BN * HH;
  float* __restrict__ c1out = out + BN + 3 * BN * HH;
  float* __restrict__ dout  = out + BN + 4 * BN * HH;

  // Weights in B-fragment chunked layout (bf16). 37KB total -> 4 blocks/CU.
  __shared__ __align__(16) short wih0L[2][NG][8];   // K=10 padded to 16
  __shared__ __align__(16) short whh0L[4][NG][8];
  __shared__ __align__(16) short wih1L[4][NG][8];
  __shared__ __align__(16) short whh1L[4][NG][8];
  __shared__ __align__(16) short tsg0[4][64][8];    // t dims 0..7 (per wave)
  __shared__ __align__(4)  short tsg1[4][64][2];    // t dims 8..9
  __shared__ __align__(16) short hsg[4][4][16][8];  // per-wave, per-st h0n staging

  const int tid = threadIdx.x;
  for (int idx = tid; idx < NG * HH; idx += 256) {  // 4096
    int n = idx >> 5, k = idx & 31;
    whh0L[k >> 3][n][k & 7] = f2bf(Whh0[n * HH + k]);
    wih1L[k >> 3][n][k & 7] = f2bf(Wih1[n * HH + k]);
    whh1L[k >> 3][n][k & 7] = f2bf(Whh1[n * HH + k]);
  }
  for (int idx = tid; idx < NG * 16; idx += 256) {  // 2048
    int n = idx >> 4, k = idx & 15;
    wih0L[k >> 3][n][k & 7] = (k < LL) ? f2bf(Wih0[n * LL + k]) : (short)0;
  }

  const int lane = tid & 63;
  const int w = tid >> 6;
  const int col = lane & 15;
  const int g = lane >> 4;

  float biasv0[8], biasv1[8];
#pragma unroll
  for (int nt = 0; nt < 8; ++nt) {
    biasv0[nt] = bih0[nt * 16 + col] + bhh0[nt * 16 + col];
    biasv1[nt] = bih1[nt * 16 + col] + bhh1[nt * 16 + col];
  }
  const float wfc0 = Wfc[col], wfc1 = Wfc[16 + col];
  const float bfcv = bfc[0];

  const int ebase = blockIdx.x * 256 + w * 64;   // this wave's 64 elements

  { // ---- t-MLP: one element per lane; weights are uniform scalar loads
    float gv = grad[ebase + lane];
    float sg = (gv > 0.f) ? 1.f : ((gv < 0.f) ? -1.f : 0.f);
    float lg = __logf(fabsf(gv) + 1e-14f);
    float u[LL], t[LL];
#pragma unroll
    for (int j = 0; j < LL; ++j)
      u[j] = ftanh(W1[2 * j] * sg + W1[2 * j + 1] * lg + b1[j]);
#pragma unroll
    for (int j = 0; j < LL; ++j) {
      float a = b2[j];
#pragma unroll
      for (int k = 0; k < LL; ++k) a += W2[j * LL + k] * u[k];
      t[j] = a;
    }
    bf16x8 tv0;
#pragma unroll
    for (int s = 0; s < 8; ++s) tv0[s] = f2bf(t[s]);
    *reinterpret_cast<bf16x8*>(&tsg0[w][lane][0]) = tv0;
    tsg1[w][lane][0] = f2bf(t[8]);
    tsg1[w][lane][1] = f2bf(t[9]);
  }
  __syncthreads();   // weights + t staging visible to all

#pragma unroll 1
  for (int st = 0; st < 4; ++st) {
    const int m16 = ebase + st * 16;
    const int mrow = 4 * g;

    // ---- issue ALL global loads for this st up front (hide HBM latency) ----
    const float4* hp = reinterpret_cast<const float4*>(h0 + (size_t)(m16 + col) * HH + 8 * g);
    float4 v0 = hp[0], v1 = hp[1];
    const float4* h1p = reinterpret_cast<const float4*>(h1 + (size_t)(m16 + col) * HH + 8 * g);
    float4 w0 = h1p[0], w1v = h1p[1];
    float c0r[2][4], c1r[2][4];
#pragma unroll
    for (int kk = 0; kk < 2; ++kk)
#pragma unroll
      for (int r = 0; r < 4; ++r) {
        c0r[kk][r] = c0[(size_t)(m16 + mrow + r) * HH + kk * 16 + col];
        c1r[kk][r] = c1[(size_t)(m16 + mrow + r) * HH + kk * 16 + col];
      }
    float4 xv = *reinterpret_cast<const float4*>(x + m16 + mrow);  // group-broadcast 16B

    // ---- layer-0 A fragments ----
    bf16x8 a_t = {0, 0, 0, 0, 0, 0, 0, 0};        // K=10 padded; g>=2 all zero
    if (g == 0) a_t = *reinterpret_cast<const bf16x8*>(&tsg0[w][st * 16 + col][0]);
    else if (g == 1) {
      a_t[0] = tsg1[w][st * 16 + col][0];
      a_t[1] = tsg1[w][st * 16 + col][1];
    }
    bf16x8 a_h0;
    a_h0[0] = f2bf(v0.x); a_h0[1] = f2bf(v0.y); a_h0[2] = f2bf(v0.z); a_h0[3] = f2bf(v0.w);
    a_h0[4] = f2bf(v1.x); a_h0[5] = f2bf(v1.y); a_h0[6] = f2bf(v1.z); a_h0[7] = f2bf(v1.w);

    f32x4 acc[8];
#pragma unroll
    for (int nt = 0; nt < 8; ++nt) {
      float bv = biasv0[nt];
      f32x4 a = {bv, bv, bv, bv};
      acc[nt] = a;
    }
#pragma unroll
    for (int nt = 0; nt < 8; ++nt) {
      bf16x8 bih = {0, 0, 0, 0, 0, 0, 0, 0};
      if (g < 2) bih = *reinterpret_cast<const bf16x8*>(&wih0L[g][nt * 16 + col][0]);
      acc[nt] = __builtin_amdgcn_mfma_f32_16x16x32_bf16(a_t, bih, acc[nt], 0, 0, 0);
      bf16x8 bhh = *reinterpret_cast<const bf16x8*>(&whh0L[g][nt * 16 + col][0]);
      acc[nt] = __builtin_amdgcn_mfma_f32_16x16x32_bf16(a_h0, bhh, acc[nt], 0, 0, 0);
    }

    // ---- layer-0 gates: lane-local in C layout (row=4g+r, k=kk*16+col) ----
#pragma unroll
    for (int kk = 0; kk < 2; ++kk) {
      const int k = kk * 16 + col;
#pragma unroll
      for (int r = 0; r < 4; ++r) {
        const size_t e2 = (size_t)(m16 + mrow + r);
        float iv = fsig(acc[0 + kk][r]);
        float fv = fsig(acc[2 + kk][r]);
        float gv = ftanh(acc[4 + kk][r]);
        float ov = fsig(acc[6 + kk][r]);
        float cn = fv * c0r[kk][r] + iv * gv;
        float hn = ov * ftanh(cn);
        c0out[e2 * HH + k] = cn;
        h0out[e2 * HH + k] = hn;
        hsg[w][k >> 3][mrow + r][k & 7] = f2bf(hn);
      }
    }
    // hsg is PER-WAVE: wave-local LDS fence is sufficient (no block barrier)
    asm volatile("s_waitcnt lgkmcnt(0)" ::: "memory");

    // ---- layer-1 A fragments ----
    bf16x8 a_hn = *reinterpret_cast<const bf16x8*>(&hsg[w][g][col][0]);
    bf16x8 a_h1;
    a_h1[0] = f2bf(w0.x);  a_h1[1] = f2bf(w0.y);  a_h1[2] = f2bf(w0.z);  a_h1[3] = f2bf(w0.w);
    a_h1[4] = f2bf(w1v.x); a_h1[5] = f2bf(w1v.y); a_h1[6] = f2bf(w1v.z); a_h1[7] = f2bf(w1v.w);

#pragma unroll
    for (int nt = 0; nt < 8; ++nt) {
      float bv = biasv1[nt];
      f32x4 a = {bv, bv, bv, bv};
      acc[nt] = a;
    }
#pragma unroll
    for (int nt = 0; nt < 8; ++nt) {
      bf16x8 bih = *reinterpret_cast<const bf16x8*>(&wih1L[g][nt * 16 + col][0]);
      acc[nt] = __builtin_amdgcn_mfma_f32_16x16x32_bf16(a_hn, bih, acc[nt], 0, 0, 0);
      bf16x8 bhh = *reinterpret_cast<const bf16x8*>(&whh1L[g][nt * 16 + col][0]);
      acc[nt] = __builtin_amdgcn_mfma_f32_16x16x32_bf16(a_h1, bhh, acc[nt], 0, 0, 0);
    }

    // ---- layer-1 gates + delta partial ----
    float dsum[4] = {0.f, 0.f, 0.f, 0.f};
#pragma unroll
    for (int kk = 0; kk < 2; ++kk) {
      const int k = kk * 16 + col;
      const float wf = kk ? wfc1 : wfc0;
#pragma unroll
      for (int r = 0; r < 4; ++r) {
        const size_t e2 = (size_t)(m16 + mrow + r);
        float iv = fsig(acc[0 + kk][r]);
        float fv = fsig(acc[2 + kk][r]);
        float gv = ftanh(acc[4 + kk][r]);
        float ov = fsig(acc[6 + kk][r]);
        float cn = fv * c1r[kk][r] + iv * gv;
        float hn = ov * ftanh(cn);
        c1out[e2 * HH + k] = cn;
        h1out[e2 * HH + k] = hn;
        dsum[r] += hn * wf;
      }
    }
    // reduce across the 16 lanes of each group (rows 4g..4g+3)
#pragma unroll
    for (int off = 1; off < 16; off <<= 1) {
#pragma unroll
      for (int r = 0; r < 4; ++r) dsum[r] += __shfl_xor(dsum[r], off, 64);
    }
    if (col == 0) {
      const int e4 = m16 + mrow;
      float4 dv = {dsum[0] + bfcv, dsum[1] + bfcv, dsum[2] + bfcv, dsum[3] + bfcv};
      *reinterpret_cast<float4*>(dout + e4) = dv;
      float4 xn = {xv.x + dv.x, xv.y + dv.y, xv.z + dv.z, xv.w + dv.w};
      *reinterpret_cast<float4*>(xout + e4) = xn;
    }
  }
}

extern "C" void kernel_launch(void* const* d_in, const int* in_sizes, int n_in,
                              void* d_out, int out_size, void* d_ws, size_t ws_size,
                              hipStream_t stream) {
  const float* x    = (const float*)d_in[0];
  const float* grad = (const float*)d_in[1];
  const float* h0   = (const float*)d_in[2];
  const float* c0   = (const float*)d_in[3];
  const float* h1   = (const float*)d_in[4];
  const float* c1   = (const float*)d_in[5];
  const float* W1   = (const float*)d_in[6];
  const float* b1   = (const float*)d_in[7];
  const float* W2   = (const float*)d_in[8];
  const float* b2   = (const float*)d_in[9];
  const float* Wih0 = (const float*)d_in[10];
  const float* Whh0 = (const float*)d_in[11];
  const float* bih0 = (const float*)d_in[12];
  const float* bhh0 = (const float*)d_in[13];
  const float* Wih1 = (const float*)d_in[14];
  const float* Whh1 = (const float*)d_in[15];
  const float* bih1 = (const float*)d_in[16];
  const float* bhh1 = (const float*)d_in[17];
  const float* Wfc  = (const float*)d_in[18];
  const float* bfc  = (const float*)d_in[19];
  const int BN = in_sizes[0];            // 800000, divisible by 256
  const int nblk = BN / 256;             // 3125 blocks x (4 waves x 64 elems)
  l2o_fused<<<nblk, 256, 0, stream>>>(x, grad, h0, c0, h1, c1, W1, b1, W2, b2,
                                      Wih0, Whh0, bih0, bhh0, Wih1, Whh1,
                                      bih1, bhh1, Wfc, bfc, (float*)d_out, BN);
}

// Round 3
// 218.281 us; speedup vs baseline: 1.3288x; 1.3288x over previous
//
#include <hip/hip_runtime.h>

// L2O optimizer fused kernel — R3: R1 structure (loads near use, no spill) +
// R2's cheap activations (v_exp + v_rcp, native bf16 cvt) + 37KB LDS.
// Layouts:
//  * B-frag LDS [k/8][n][k%8] (bf16): lane l reads 16B at [l>>4][nt*16+(l&15)].
//  * A and B frags use the SAME k-slot mapping -> correctness independent of HW k-order.
//  * C/D layout (HW-verified): col = lane&15, row = (lane>>4)*4 + reg.

typedef __attribute__((ext_vector_type(8))) short bf16x8;
typedef __attribute__((ext_vector_type(4))) float f32x4;

#define HH 32
#define LL 10
#define NG 128

__device__ __forceinline__ short f2bf(float x) {
  __bf16 b = (__bf16)x;                 // HW v_cvt (pairs fuse to v_cvt_pk_bf16_f32)
  return __builtin_bit_cast(short, b);
}
__device__ __forceinline__ float fsig(float x) {
  return __builtin_amdgcn_rcpf(1.0f + __expf(-x));
}
__device__ __forceinline__ float ftanh(float x) {
  return fmaf(2.0f, __builtin_amdgcn_rcpf(1.0f + __expf(-2.0f * x)), -1.0f);
}

__global__ __launch_bounds__(256, 3) void l2o_fused(
    const float* __restrict__ x, const float* __restrict__ grad,
    const float* __restrict__ h0, const float* __restrict__ c0,
    const float* __restrict__ h1, const float* __restrict__ c1,
    const float* __restrict__ W1, const float* __restrict__ b1,
    const float* __restrict__ W2, const float* __restrict__ b2,
    const float* __restrict__ Wih0, const float* __restrict__ Whh0,
    const float* __restrict__ bih0, const float* __restrict__ bhh0,
    const float* __restrict__ Wih1, const float* __restrict__ Whh1,
    const float* __restrict__ bih1, const float* __restrict__ bhh1,
    const float* __restrict__ Wfc, const float* __restrict__ bfc,
    float* __restrict__ out, int BNi)
{
  const size_t BN = (size_t)BNi;
  float* __restrict__ xout  = out;
  float* __restrict__ h0out = out + BN;
  float* __restrict__ c0out = out + BN + BN * HH;
  float* __restrict__ h1out = out + BN + 2 * BN * HH;
  float* __restrict__ c1out = out + BN + 3 * BN * HH;
  float* __restrict__ dout  = out + BN + 4 * BN * HH;

  // Weights in B-fragment chunked layout (bf16). 37KB total -> 4 blocks/CU via LDS.
  __shared__ __align__(16) short wih0L[2][NG][8];   // K=10 padded to 16
  __shared__ __align__(16) short whh0L[4][NG][8];
  __shared__ __align__(16) short wih1L[4][NG][8];
  __shared__ __align__(16) short whh1L[4][NG][8];
  __shared__ __align__(16) short tsg0[4][64][8];    // t dims 0..7 (per wave)
  __shared__ __align__(4)  short tsg1[4][64][2];    // t dims 8..9
  __shared__ __align__(16) short hsg[4][4][16][8];  // per-wave, per-st h0n staging

  const int tid = threadIdx.x;
  for (int idx = tid; idx < NG * HH; idx += 256) {  // 4096
    int n = idx >> 5, k = idx & 31;
    whh0L[k >> 3][n][k & 7] = f2bf(Whh0[n * HH + k]);
    wih1L[k >> 3][n][k & 7] = f2bf(Wih1[n * HH + k]);
    whh1L[k >> 3][n][k & 7] = f2bf(Whh1[n * HH + k]);
  }
  for (int idx = tid; idx < NG * 16; idx += 256) {  // 2048
    int n = idx >> 4, k = idx & 15;
    wih0L[k >> 3][n][k & 7] = (k < LL) ? f2bf(Wih0[n * LL + k]) : (short)0;
  }

  const int lane = tid & 63;
  const int w = tid >> 6;
  const int col = lane & 15;
  const int g = lane >> 4;

  float biasv0[8], biasv1[8];
#pragma unroll
  for (int nt = 0; nt < 8; ++nt) {
    biasv0[nt] = bih0[nt * 16 + col] + bhh0[nt * 16 + col];
    biasv1[nt] = bih1[nt * 16 + col] + bhh1[nt * 16 + col];
  }
  const float wfc0 = Wfc[col], wfc1 = Wfc[16 + col];
  const float bfcv = bfc[0];

  const int ebase = blockIdx.x * 256 + w * 64;   // this wave's 64 elements

  { // ---- t-MLP: one element per lane; weights are uniform scalar loads
    float gv = grad[ebase + lane];
    float sg = (gv > 0.f) ? 1.f : ((gv < 0.f) ? -1.f : 0.f);
    float lg = __logf(fabsf(gv) + 1e-14f);
    float u[LL], t[LL];
#pragma unroll
    for (int j = 0; j < LL; ++j)
      u[j] = ftanh(W1[2 * j] * sg + W1[2 * j + 1] * lg + b1[j]);
#pragma unroll
    for (int j = 0; j < LL; ++j) {
      float a = b2[j];
#pragma unroll
      for (int k = 0; k < LL; ++k) a += W2[j * LL + k] * u[k];
      t[j] = a;
    }
    bf16x8 tv0;
#pragma unroll
    for (int s = 0; s < 8; ++s) tv0[s] = f2bf(t[s]);
    *reinterpret_cast<bf16x8*>(&tsg0[w][lane][0]) = tv0;
    tsg1[w][lane][0] = f2bf(t[8]);
    tsg1[w][lane][1] = f2bf(t[9]);
  }
  __syncthreads();   // weights + t staging visible to all

#pragma unroll 1
  for (int st = 0; st < 4; ++st) {
    const int m16 = ebase + st * 16;
    const int mrow = 4 * g;

    // ---- layer-0 A fragments ----
    bf16x8 a_t = {0, 0, 0, 0, 0, 0, 0, 0};        // K=10 padded; g>=2 all zero
    if (g == 0) a_t = *reinterpret_cast<const bf16x8*>(&tsg0[w][st * 16 + col][0]);
    else if (g == 1) {
      a_t[0] = tsg1[w][st * 16 + col][0];
      a_t[1] = tsg1[w][st * 16 + col][1];
    }
    const float4* hp = reinterpret_cast<const float4*>(h0 + (size_t)(m16 + col) * HH + 8 * g);
    float4 v0 = hp[0], v1 = hp[1];
    bf16x8 a_h0;
    a_h0[0] = f2bf(v0.x); a_h0[1] = f2bf(v0.y); a_h0[2] = f2bf(v0.z); a_h0[3] = f2bf(v0.w);
    a_h0[4] = f2bf(v1.x); a_h0[5] = f2bf(v1.y); a_h0[6] = f2bf(v1.z); a_h0[7] = f2bf(v1.w);

    // c0 loads issued here so HBM latency hides under layer-0 MFMAs
    float c0r[2][4];
#pragma unroll
    for (int kk = 0; kk < 2; ++kk)
#pragma unroll
      for (int r = 0; r < 4; ++r)
        c0r[kk][r] = c0[(size_t)(m16 + mrow + r) * HH + kk * 16 + col];

    f32x4 acc[8];
#pragma unroll
    for (int nt = 0; nt < 8; ++nt) {
      float bv = biasv0[nt];
      f32x4 a = {bv, bv, bv, bv};
      acc[nt] = a;
    }
#pragma unroll
    for (int nt = 0; nt < 8; ++nt) {
      bf16x8 bih = {0, 0, 0, 0, 0, 0, 0, 0};
      if (g < 2) bih = *reinterpret_cast<const bf16x8*>(&wih0L[g][nt * 16 + col][0]);
      acc[nt] = __builtin_amdgcn_mfma_f32_16x16x32_bf16(a_t, bih, acc[nt], 0, 0, 0);
      bf16x8 bhh = *reinterpret_cast<const bf16x8*>(&whh0L[g][nt * 16 + col][0]);
      acc[nt] = __builtin_amdgcn_mfma_f32_16x16x32_bf16(a_h0, bhh, acc[nt], 0, 0, 0);
    }

    // issue h1 loads now: in flight during layer-0 gate VALU work
    const float4* h1p = reinterpret_cast<const float4*>(h1 + (size_t)(m16 + col) * HH + 8 * g);
    float4 w0 = h1p[0], w1v = h1p[1];

    // ---- layer-0 gates: lane-local in C layout (row=4g+r, k=kk*16+col) ----
#pragma unroll
    for (int kk = 0; kk < 2; ++kk) {
      const int k = kk * 16 + col;
#pragma unroll
      for (int r = 0; r < 4; ++r) {
        const size_t e2 = (size_t)(m16 + mrow + r);
        float iv = fsig(acc[0 + kk][r]);
        float fv = fsig(acc[2 + kk][r]);
        float gv = ftanh(acc[4 + kk][r]);
        float ov = fsig(acc[6 + kk][r]);
        float cn = fv * c0r[kk][r] + iv * gv;
        float hn = ov * ftanh(cn);
        c0out[e2 * HH + k] = cn;
        h0out[e2 * HH + k] = hn;
        hsg[w][k >> 3][mrow + r][k & 7] = f2bf(hn);
      }
    }
    // hsg is PER-WAVE: wave-local LDS fence is sufficient (no block barrier)
    asm volatile("s_waitcnt lgkmcnt(0)" ::: "memory");

    // ---- layer-1 A fragments ----
    bf16x8 a_hn = *reinterpret_cast<const bf16x8*>(&hsg[w][g][col][0]);
    bf16x8 a_h1;
    a_h1[0] = f2bf(w0.x);  a_h1[1] = f2bf(w0.y);  a_h1[2] = f2bf(w0.z);  a_h1[3] = f2bf(w0.w);
    a_h1[4] = f2bf(w1v.x); a_h1[5] = f2bf(w1v.y); a_h1[6] = f2bf(w1v.z); a_h1[7] = f2bf(w1v.w);

    // c1 loads hide under layer-1 MFMAs
    float c1r[2][4];
#pragma unroll
    for (int kk = 0; kk < 2; ++kk)
#pragma unroll
      for (int r = 0; r < 4; ++r)
        c1r[kk][r] = c1[(size_t)(m16 + mrow + r) * HH + kk * 16 + col];

#pragma unroll
    for (int nt = 0; nt < 8; ++nt) {
      float bv = biasv1[nt];
      f32x4 a = {bv, bv, bv, bv};
      acc[nt] = a;
    }
#pragma unroll
    for (int nt = 0; nt < 8; ++nt) {
      bf16x8 bih = *reinterpret_cast<const bf16x8*>(&wih1L[g][nt * 16 + col][0]);
      acc[nt] = __builtin_amdgcn_mfma_f32_16x16x32_bf16(a_hn, bih, acc[nt], 0, 0, 0);
      bf16x8 bhh = *reinterpret_cast<const bf16x8*>(&whh1L[g][nt * 16 + col][0]);
      acc[nt] = __builtin_amdgcn_mfma_f32_16x16x32_bf16(a_h1, bhh, acc[nt], 0, 0, 0);
    }

    // ---- layer-1 gates + delta partial ----
    float dsum[4] = {0.f, 0.f, 0.f, 0.f};
#pragma unroll
    for (int kk = 0; kk < 2; ++kk) {
      const int k = kk * 16 + col;
      const float wf = kk ? wfc1 : wfc0;
#pragma unroll
      for (int r = 0; r < 4; ++r) {
        const size_t e2 = (size_t)(m16 + mrow + r);
        float iv = fsig(acc[0 + kk][r]);
        float fv = fsig(acc[2 + kk][r]);
        float gv = ftanh(acc[4 + kk][r]);
        float ov = fsig(acc[6 + kk][r]);
        float cn = fv * c1r[kk][r] + iv * gv;
        float hn = ov * ftanh(cn);
        c1out[e2 * HH + k] = cn;
        h1out[e2 * HH + k] = hn;
        dsum[r] += hn * wf;
      }
    }
    // reduce across the 16 lanes of each group (rows 4g..4g+3)
#pragma unroll
    for (int off = 1; off < 16; off <<= 1) {
#pragma unroll
      for (int r = 0; r < 4; ++r) dsum[r] += __shfl_xor(dsum[r], off, 64);
    }
    if (col == 0) {
      const int e4 = m16 + mrow;
      float4 xv = *reinterpret_cast<const float4*>(x + e4);
      float4 dv = {dsum[0] + bfcv, dsum[1] + bfcv, dsum[2] + bfcv, dsum[3] + bfcv};
      *reinterpret_cast<float4*>(dout + e4) = dv;
      float4 xn = {xv.x + dv.x, xv.y + dv.y, xv.z + dv.z, xv.w + dv.w};
      *reinterpret_cast<float4*>(xout + e4) = xn;
    }
  }
}

extern "C" void kernel_launch(void* const* d_in, const int* in_sizes, int n_in,
                              void* d_out, int out_size, void* d_ws, size_t ws_size,
                              hipStream_t stream) {
  const float* x    = (const float*)d_in[0];
  const float* grad = (const float*)d_in[1];
  const float* h0   = (const float*)d_in[2];
  const float* c0   = (const float*)d_in[3];
  const float* h1   = (const float*)d_in[4];
  const float* c1   = (const float*)d_in[5];
  const float* W1   = (const float*)d_in[6];
  const float* b1   = (const float*)d_in[7];
  const float* W2   = (const float*)d_in[8];
  const float* b2   = (const float*)d_in[9];
  const float* Wih0 = (const float*)d_in[10];
  const float* Whh0 = (const float*)d_in[11];
  const float* bih0 = (const float*)d_in[12];
  const float* bhh0 = (const float*)d_in[13];
  const float* Wih1 = (const float*)d_in[14];
  const float* Whh1 = (const float*)d_in[15];
  const float* bih1 = (const float*)d_in[16];
  const float* bhh1 = (const float*)d_in[17];
  const float* Wfc  = (const float*)d_in[18];
  const float* bfc  = (const float*)d_in[19];
  const int BN = in_sizes[0];            // 800000, divisible by 256
  const int nblk = BN / 256;             // 3125 blocks x (4 waves x 64 elems)
  l2o_fused<<<nblk, 256, 0, stream>>>(x, grad, h0, c0, h1, c1, W1, b1, W2, b2,
                                      Wih0, Whh0, bih0, bhh0, Wih1, Whh1,
                                      bih1, bhh1, Wfc, bfc, (float*)d_out, BN);
}